// Round 17
// baseline (211.451 us; speedup 1.0000x reference)
//
#include <hip/hip_runtime.h>
#include <hip/hip_bf16.h>
#include <math.h>

#define TARLEN 263680
#define POWEXP 2.302585092994046f  // ln(10)
#define PC(i) ((i) + ((i) >> 3))   // complex-unit LDS padding (1 per 8)

typedef __attribute__((ext_vector_type(8))) short bf16x8;
typedef __attribute__((ext_vector_type(8))) ushort u16x8;
typedef __attribute__((ext_vector_type(4))) float f32x4;

__device__ __forceinline__ void gload16(const void* g, void* l) {
    __builtin_amdgcn_global_load_lds((const __attribute__((address_space(1))) void*)g,
                                     (__attribute__((address_space(3))) void*)l, 16, 0, 0);
}

__device__ __forceinline__ float bf16f(ushort u) {
    union { uint u; float f; } v; v.u = (uint)u << 16; return v.f;
}
__device__ __forceinline__ ushort fbf16(float x) {
    __hip_bfloat16 h = __float2bfloat16(x);
    return *reinterpret_cast<ushort*>(&h);
}

// sin/cos with input in REVOLUTIONS (v_sin_f32 native domain); args are exact
// binary fractions -> no rounding, no range reduction.
__device__ __forceinline__ float vsin_rev(float rev) {
    float r; asm("v_sin_f32 %0, %1" : "=v"(r) : "v"(rev)); return r;
}
__device__ __forceinline__ float vcos_rev(float rev) {
    float r; asm("v_cos_f32 %0, %1" : "=v"(r) : "v"(rev)); return r;
}

// ============ GEMM layer 0 (no norm): 128x128 tile, 512 thr (r16) ===========
__global__ __launch_bounds__(512) void gemm8(
    const ushort* __restrict__ A, const ushort* __restrict__ Bt,
    const float* __restrict__ bias, ushort* __restrict__ C,
    int K, float* __restrict__ ps, float* __restrict__ pq)
{
    __shared__ ushort As[3][4096];
    __shared__ ushort Bs[3][4096];
    __shared__ float sred[8][2][16];
    __shared__ float qred[8][2][16];
    const int tid = threadIdx.x;
    const int lane = tid & 63;
    const int wid = tid >> 6;
    const int nwg = gridDim.x * gridDim.y;
    const int bid = blockIdx.y * gridDim.x + blockIdx.x;
    const int q8 = nwg >> 3;
    const int swzb = (bid & 7) * q8 + (bid >> 3);
    const int bx = swzb % gridDim.x;
    const int by = swzb / gridDim.x;
    const int m0 = by * 128;
    const int n0 = bx * 128;
    const int NT = K >> 5;

    f32x4 acc[4][2];
#pragma unroll
    for (int m = 0; m < 4; ++m)
#pragma unroll
        for (int n = 0; n < 2; ++n)
            acc[m][n] = (f32x4){0.f, 0.f, 0.f, 0.f};

    const int srow = tid >> 2;
    const int scol = (((tid & 3) ^ ((tid >> 3) & 3)) << 3);

    auto stage = [&](int t, int buf) {
        const int k0 = t << 5;
        gload16(A + (size_t)(m0 + srow) * K + k0 + scol, &As[buf][tid * 8]);
        gload16(Bt + (size_t)(n0 + srow) * K + k0 + scol, &Bs[buf][tid * 8]);
    };

    const int lr = lane & 15;
    const int sw8 = (((lane >> 4) ^ ((lane >> 1) & 3)) << 3);
    const int wm0 = (wid >> 2) * 64;
    const int wn0 = (wid & 3) * 32;

    stage(0, 0);
    stage(1, 1);
    for (int t = 0; t < NT; ++t) {
        const int cur = t % 3;
        if (t + 2 < NT) {
            asm volatile("s_waitcnt vmcnt(2)" ::: "memory");
            __builtin_amdgcn_s_barrier();
            stage(t + 2, (t + 2) % 3);
        } else {
            asm volatile("s_waitcnt vmcnt(0)" ::: "memory");
            __builtin_amdgcn_s_barrier();
        }
        const ushort* as = As[cur];
        const ushort* bs = Bs[cur];
        bf16x8 af[4], bfv[2];
#pragma unroll
        for (int m = 0; m < 4; ++m)
            af[m] = *reinterpret_cast<const bf16x8*>(&as[(wm0 + m * 16 + lr) * 32 + sw8]);
#pragma unroll
        for (int n = 0; n < 2; ++n)
            bfv[n] = *reinterpret_cast<const bf16x8*>(&bs[(wn0 + n * 16 + lr) * 32 + sw8]);
#pragma unroll
        for (int m = 0; m < 4; ++m)
#pragma unroll
            for (int n = 0; n < 2; ++n)
                acc[m][n] = __builtin_amdgcn_mfma_f32_16x16x32_bf16(af[m], bfv[n], acc[m][n], 0, 0, 0);
    }
    __syncthreads();

    const int cr = (lane >> 4) << 2;
    const int cc = lane & 15;
    float sacc[2] = {0.f, 0.f}, qacc[2] = {0.f, 0.f};
#pragma unroll
    for (int m = 0; m < 4; ++m) {
#pragma unroll
        for (int n = 0; n < 2; ++n) {
            int gcol = n0 + wn0 + n * 16 + cc;
            float bv = bias[gcol];
            int grow = m0 + wm0 + m * 16 + cr;
#pragma unroll
            for (int j = 0; j < 4; ++j) {
                float v = acc[m][n][j] + bv;
                sacc[n] += v;
                qacc[n] += v * v;
                C[(size_t)(grow + j) * 512 + gcol] = fbf16(v);
            }
        }
    }
#pragma unroll
    for (int n = 0; n < 2; ++n) {
        float s = sacc[n], q = qacc[n];
        s += __shfl_xor(s, 16); q += __shfl_xor(q, 16);
        s += __shfl_xor(s, 32); q += __shfl_xor(q, 32);
        if (lane < 16) { sred[wid][n][lane] = s; qred[wid][n][lane] = q; }
    }
    __syncthreads();
    if (tid < 128) {
        int wn_ = tid >> 5, n_ = (tid >> 4) & 1, cc_ = tid & 15;
        float s = sred[wn_][n_][cc_] + sred[4 + wn_][n_][cc_];
        float q = qred[wn_][n_][cc_] + qred[4 + wn_][n_][cc_];
        int col = n0 + wn_ * 32 + n_ * 16 + cc_;
        ps[(size_t)by * 512 + col] = s;
        pq[(size_t)by * 512 + col] = q;
    }
}

// ============ GEMM+BN, 64x128 tile, 256 thr (4 waves of 64x32) ==============
// M-split for 2+ blocks/CU (grid 512-1152 blocks). A-tile 64x32 reg-staged
// (global->reg->affine+lrelu->ds_write), B-tile 128x32 via 2x gload_lds.
// 3 vm-ops/stage -> counted vmcnt(3), 3-buffer depth-2 pipeline. All waves
// share A rows; each wave owns a 32-col strip -> per-wave stats complete.
template<int EPI>
__global__ __launch_bounds__(256) void gemm4n(
    const ushort* __restrict__ H, const ushort* __restrict__ Bt,
    const float* __restrict__ bias,
    const float* __restrict__ psIn, const float* __restrict__ pqIn, int ngIn,
    const float* __restrict__ gamma, const float* __restrict__ beta,
    ushort* __restrict__ C, int K, int Nvalid, int ldc,
    float* __restrict__ psOut, float* __restrict__ pqOut)
{
    __shared__ ushort As[3][2048];   // [64][32]
    __shared__ ushort Bs[3][4096];   // [128][32]
    __shared__ uint sab[512];
    const int tid = threadIdx.x;
    const int lane = tid & 63;
    const int wid = tid >> 6;
    // bijective XCD swizzle (nwg % 8 == 0: 512, 1152)
    const int nwg = gridDim.x * gridDim.y;
    const int bid = blockIdx.y * gridDim.x + blockIdx.x;
    const int q8 = nwg >> 3;
    const int swzb = (bid & 7) * q8 + (bid >> 3);
    const int bx = swzb % gridDim.x;
    const int by = swzb / gridDim.x;
    const int m0 = by * 64;
    const int n0 = bx * 128;
    const int NT = K >> 5;  // 16 (even)

    // stats prologue: per-column affine a*x+b (packed bf16)
    for (int c = tid; c < 512; c += 256) {
        float s = 0.f, q = 0.f;
#pragma unroll 4
        for (int rg = 0; rg < ngIn; ++rg) { s += psIn[rg * 512 + c]; q += pqIn[rg * 512 + c]; }
        float m = s * (1.f / 8192.f);
        float v = q * (1.f / 8192.f) - m * m;
        float a = rsqrtf(v + 1e-5f) * gamma[c];
        float b = beta[c] - m * a;
        sab[c] = (uint)fbf16(a) | ((uint)fbf16(b) << 16);
    }

    f32x4 acc[4][2];
#pragma unroll
    for (int m = 0; m < 4; ++m)
#pragma unroll
        for (int n = 0; n < 2; ++n)
            acc[m][n] = (f32x4){0.f, 0.f, 0.f, 0.f};

    const int srow = tid >> 2;                              // 0..63
    const int scol = (((tid & 3) ^ ((tid >> 3) & 3)) << 3); // swizzled src chunk
    const int lr = lane & 15;
    const int sw8 = (((lane >> 4) ^ ((lane >> 1) & 3)) << 3);
    const int wn0 = wid * 32;

    const size_t arow  = (size_t)(m0 + srow) * K + scol;
    const size_t brow0 = (size_t)(n0 + srow) * K + scol;
    const size_t brow1 = (size_t)(n0 + 64 + srow) * K + scol;

    auto stageB = [&](int t, int buf) {
        gload16(Bt + brow0 + (t << 5), &Bs[buf][tid * 8]);
        gload16(Bt + brow1 + (t << 5), &Bs[buf][2048 + tid * 8]);
    };
    auto loadA = [&](int t, u16x8& dst) {
        dst = *reinterpret_cast<const u16x8*>(H + arow + (t << 5));
    };

    __syncthreads();  // sab ready

    u16x8 a0, a1;
    stageB(0, 0); loadA(0, a0);
    stageB(1, 1); loadA(1, a1);

    auto iter = [&](int t, u16x8& ar) {
        const int cur = t % 3;
        if (t + 2 < NT) asm volatile("s_waitcnt vmcnt(3)" ::: "memory");
        else            asm volatile("s_waitcnt vmcnt(0)" ::: "memory");
        // transform A-reg -> LDS (affine + leaky-relu + bf16)
        {
            const uint* pk = &sab[(t << 5) + scol];
            u16x8 o;
#pragma unroll
            for (int j = 0; j < 8; ++j) {
                uint w = pk[j];
                float a = bf16f((ushort)(w & 0xffffu));
                float b = bf16f((ushort)(w >> 16));
                float y = fmaf(bf16f(ar[j]), a, b);
                o[j] = fbf16(y >= 0.f ? y : 0.2f * y);
            }
            *reinterpret_cast<u16x8*>(&As[cur][tid * 8]) = o;
        }
        asm volatile("s_waitcnt lgkmcnt(0)" ::: "memory");
        __builtin_amdgcn_s_barrier();
        if (t + 2 < NT) { stageB(t + 2, (t + 2) % 3); loadA(t + 2, ar); }
        const ushort* as = As[cur];
        const ushort* bs = Bs[cur];
        bf16x8 af[4], bfv[2];
#pragma unroll
        for (int m = 0; m < 4; ++m)
            af[m] = *reinterpret_cast<const bf16x8*>(&as[(m * 16 + lr) * 32 + sw8]);
#pragma unroll
        for (int n = 0; n < 2; ++n)
            bfv[n] = *reinterpret_cast<const bf16x8*>(&bs[(wn0 + n * 16 + lr) * 32 + sw8]);
#pragma unroll
        for (int m = 0; m < 4; ++m)
#pragma unroll
            for (int n = 0; n < 2; ++n)
                acc[m][n] = __builtin_amdgcn_mfma_f32_16x16x32_bf16(af[m], bfv[n], acc[m][n], 0, 0, 0);
    };

    for (int t = 0; t < NT; t += 2) { iter(t, a0); iter(t + 1, a1); }

    // epilogue: C/D layout col=lane&15, row=(lane>>4)*4+reg
    const int cr = (lane >> 4) << 2;
    const int cc = lane & 15;
    float sacc[2] = {0.f, 0.f}, qacc[2] = {0.f, 0.f};
#pragma unroll
    for (int m = 0; m < 4; ++m) {
#pragma unroll
        for (int n = 0; n < 2; ++n) {
            int gcol = n0 + wn0 + n * 16 + cc;
            if (EPI == 0 || gcol < Nvalid) {
                float bv = bias[gcol];
                int grow = m0 + m * 16 + cr;
#pragma unroll
                for (int j = 0; j < 4; ++j) {
                    float v = acc[m][n][j] + bv;
                    if (EPI == 1) {
                        float sg = 1.f / (1.f + __expf(-v));
                        v = 2.f * __expf(POWEXP * __logf(sg)) + 1e-7f;
                    } else {
                        sacc[n] += v;
                        qacc[n] += v * v;
                    }
                    C[(size_t)(grow + j) * ldc + gcol] = fbf16(v);
                }
            }
        }
    }
    if (EPI == 0) {
#pragma unroll
        for (int n = 0; n < 2; ++n) {
            float s = sacc[n], q = qacc[n];
            s += __shfl_xor(s, 16); q += __shfl_xor(q, 16);
            s += __shfl_xor(s, 32); q += __shfl_xor(q, 32);
            if (lane < 16) {
                int col = n0 + wn0 + n * 16 + lane;
                psOut[(size_t)by * 512 + col] = s;
                pqOut[(size_t)by * 512 + col] = q;
            }
        }
    }
}

// ---------------- batched input prep: 4 weight transposes + z cast --------
__global__ __launch_bounds__(256) void prep_inputs(
    const float* __restrict__ w0, const float* __restrict__ w1,
    const float* __restrict__ w2, const float* __restrict__ w3,
    const float* __restrict__ z,
    ushort* __restrict__ B0, ushort* __restrict__ B1,
    ushort* __restrict__ B2, ushort* __restrict__ B3,
    ushort* __restrict__ A)
{
    if (blockIdx.z == 4) {
        int bid = blockIdx.y * gridDim.x + blockIdx.x;
        if (bid >= 512) return;
        int idx = (bid * 256 + threadIdx.x) << 3;
        float4 a = *reinterpret_cast<const float4*>(&z[idx]);
        float4 b = *reinterpret_cast<const float4*>(&z[idx + 4]);
        float x[8] = {a.x, a.y, a.z, a.w, b.x, b.y, b.z, b.w};
        u16x8 o;
#pragma unroll
        for (int j = 0; j < 8; ++j) o[j] = fbf16(x[j]);
        *reinterpret_cast<u16x8*>(&A[idx]) = o;
        return;
    }
    const float* w; ushort* Bt; int K, N, GX, GY;
    switch (blockIdx.z) {
        case 0: w = w0; Bt = B0; K = 128; N = 512;  GX = 4;  GY = 16; break;
        case 1: w = w1; Bt = B1; K = 512; N = 512;  GX = 16; GY = 16; break;
        case 2: w = w2; Bt = B2; K = 512; N = 512;  GX = 16; GY = 16; break;
        default:w = w3; Bt = B3; K = 512; N = 1025; GX = 16; GY = 36; break;
    }
    if ((int)blockIdx.x >= GX || (int)blockIdx.y >= GY) return;
    __shared__ float tile[32][33];
    int k0 = blockIdx.x * 32, n0 = blockIdx.y * 32;
    int tx = threadIdx.x & 31, ty = threadIdx.x >> 5;
#pragma unroll
    for (int r = 0; r < 4; ++r) {
        int k = k0 + ty + r * 8;
        int n = n0 + tx;
        tile[ty + r * 8][tx] = (n < N) ? w[(size_t)k * N + n] : 0.f;
    }
    __syncthreads();
#pragma unroll
    for (int r = 0; r < 4; ++r) {
        int n = n0 + ty + r * 8;
        int k = k0 + tx;
        Bt[(size_t)n * K + k] = fbf16(tile[tx][ty + r * 8]);
    }
}

// ---------------- Stockham radix-4 FFT, float2 LDS, 256 threads (r16) -----
__device__ __forceinline__ float2 cmul(float2 a, float c, float s) {
    return make_float2(a.x * c - a.y * s, a.x * s + a.y * c);
}

template<bool INV, int L>
__device__ __forceinline__ void stk_stage(
    const float2* __restrict__ s, float2* __restrict__ d, int t)
{
    int k = t & (L - 1);
    float2 x0 = s[PC(t)];
    float2 x1 = s[PC(t + 256)];
    float2 x2 = s[PC(t + 512)];
    float2 x3 = s[PC(t + 768)];
    if (L > 1) {
        float rev = (float)k * (1.0f / (float)(4 * L));
        float s1 = vsin_rev(rev), c1 = vcos_rev(rev);
        if (!INV) s1 = -s1;
        float c2 = c1 * c1 - s1 * s1, s2 = 2.f * c1 * s1;
        float c3 = c2 * c1 - s2 * s1, s3 = s2 * c1 + c2 * s1;
        x1 = cmul(x1, c1, s1);
        x2 = cmul(x2, c2, s2);
        x3 = cmul(x3, c3, s3);
    }
    float2 a = make_float2(x0.x + x2.x, x0.y + x2.y);
    float2 b = make_float2(x0.x - x2.x, x0.y - x2.y);
    float2 c = make_float2(x1.x + x3.x, x1.y + x3.y);
    float2 e = make_float2(x1.x - x3.x, x1.y - x3.y);
    int db = ((t - k) << 2) + k;
    d[PC(db)]         = make_float2(a.x + c.x, a.y + c.y);
    d[PC(db + 2 * L)] = make_float2(a.x - c.x, a.y - c.y);
    if (!INV) {
        d[PC(db + L)]     = make_float2(b.x + e.y, b.y - e.x);
        d[PC(db + 3 * L)] = make_float2(b.x - e.y, b.y + e.x);
    } else {
        d[PC(db + L)]     = make_float2(b.x - e.y, b.y + e.x);
        d[PC(db + 3 * L)] = make_float2(b.x + e.y, b.y - e.x);
    }
}

// audio = irfft( rfft(noise_row) * H ), H[k] = (-1)^k*(0.5 fc[k]+0.25 fc[k-1]+0.25 fc[k+1])
// (analytic collapse of rfft(fftshift(irfft(fc)*FW))). 1/1024 folded into H.
__global__ __launch_bounds__(256) void fft_filter_kernel(
    const float* __restrict__ noise, const ushort* __restrict__ fcsb,
    ushort* __restrict__ awb)
{
    __shared__ float2 X[1152], Y[1152];
    __shared__ float F[1025];
    const int tid = threadIdx.x;
    const int r = blockIdx.x;

    const float2* nrow = reinterpret_cast<const float2*>(noise + ((size_t)r << 11));
    for (int i = tid; i < 1025; i += 256) F[i] = bf16f(fcsb[(size_t)r * 1040 + i]);
    {
        float2 x0 = nrow[tid], x1 = nrow[tid + 256], x2 = nrow[tid + 512], x3 = nrow[tid + 768];
        float2 a = make_float2(x0.x + x2.x, x0.y + x2.y);
        float2 b = make_float2(x0.x - x2.x, x0.y - x2.y);
        float2 c = make_float2(x1.x + x3.x, x1.y + x3.y);
        float2 e = make_float2(x1.x - x3.x, x1.y - x3.y);
        int db = tid << 2;
        Y[PC(db)]     = make_float2(a.x + c.x, a.y + c.y);
        Y[PC(db + 1)] = make_float2(b.x + e.y, b.y - e.x);
        Y[PC(db + 2)] = make_float2(a.x - c.x, a.y - c.y);
        Y[PC(db + 3)] = make_float2(b.x - e.y, b.y + e.x);
    }
    __syncthreads();
    stk_stage<false, 4>(Y, X, tid);   __syncthreads();
    stk_stage<false, 16>(X, Y, tid);  __syncthreads();
    stk_stage<false, 64>(Y, X, tid);  __syncthreads();
    stk_stage<false, 256>(X, Y, tid); __syncthreads();

    const float INV1024 = 1.0f / 1024.0f;
    auto proc = [&](int k, float c, float s) {
        int k2 = (1024 - k) & 1023;
        float2 za = Y[PC(k)], zb = Y[PC(k2)];
        float Fer = 0.5f * (za.x + zb.x), Fei = 0.5f * (za.y - zb.y);
        float For = 0.5f * (za.y + zb.y), Foi = 0.5f * (zb.x - za.x);
        float wFr = c * For - s * Foi;
        float wFi = c * Foi + s * For;
        float Xkr = Fer + wFr, Xki = Fei + wFi;
        float Xbr = Fer - wFr, Xbi = wFi - Fei;
        float Hk, Hb;
        {
            float cl = (k == 0) ? F[1] : F[k - 1];
            float crr = (k == 1024) ? F[1023] : F[k + 1];
            float h = 0.5f * F[k] + 0.25f * (cl + crr);
            Hk = ((k & 1) ? -h : h) * INV1024;
        }
        {
            int kb = 1024 - k;
            float cl = (kb == 0) ? F[1] : F[kb - 1];
            float crr = (kb == 1024) ? F[1023] : F[kb + 1];
            float h = 0.5f * F[kb] + 0.25f * (cl + crr);
            Hb = ((kb & 1) ? -h : h) * INV1024;
        }
        float Ykr = Hk * Xkr, Yki = Hk * Xki;
        float Ybr = Hb * Xbr, Ybi = Hb * Xbi;
        if (k == 0) {
            X[PC(0)] = make_float2(0.5f * (Ykr + Ybr), 0.5f * (Ykr - Ybr));
        } else {
            float Ger = 0.5f * (Ykr + Ybr), Gei = 0.5f * (Yki - Ybi);
            float Sgr = 0.5f * (Ykr - Ybr), Sgi = 0.5f * (Yki + Ybi);
            float wpr = c, wpi = -s;
            float Gor = wpr * Sgr - wpi * Sgi;
            float Goi = wpr * Sgi + wpi * Sgr;
            X[PC(k)]  = make_float2(Ger - Goi, Gei + Gor);
            X[PC(k2)] = make_float2(Ger + Goi, Gor - Gei);
        }
    };
    {
        float rev0 = (float)tid * (1.0f / 2048.0f);
        float c0 = vcos_rev(rev0), s0 = -vsin_rev(rev0);
        proc(tid, c0, s0);
        float rev1 = (float)(tid + 256) * (1.0f / 2048.0f);
        float c1 = vcos_rev(rev1), s1 = -vsin_rev(rev1);
        proc(tid + 256, c1, s1);
        if (tid == 0) proc(512, 0.f, -1.f);
    }
    __syncthreads();

    stk_stage<true, 1>(X, Y, tid);  __syncthreads();
    stk_stage<true, 4>(Y, X, tid);  __syncthreads();
    stk_stage<true, 16>(X, Y, tid); __syncthreads();
    stk_stage<true, 64>(Y, X, tid); __syncthreads();

    {
        const int g = r & 511;
        ushort2* awrow = reinterpret_cast<ushort2*>(awb + ((size_t)r << 11));
        int t = tid;
        float2 x0 = X[PC(t)], x1 = X[PC(t + 256)], x2 = X[PC(t + 512)], x3 = X[PC(t + 768)];
        float rev = (float)t * (1.0f / 1024.0f);
        float s1 = vsin_rev(rev), c1 = vcos_rev(rev);
        float c2 = c1 * c1 - s1 * s1, s2 = 2.f * c1 * s1;
        float c3 = c2 * c1 - s2 * s1, s3 = s2 * c1 + c2 * s1;
        x1 = cmul(x1, c1, s1);
        x2 = cmul(x2, c2, s2);
        x3 = cmul(x3, c3, s3);
        float2 a = make_float2(x0.x + x2.x, x0.y + x2.y);
        float2 b = make_float2(x0.x - x2.x, x0.y - x2.y);
        float2 c = make_float2(x1.x + x3.x, x1.y + x3.y);
        float2 e = make_float2(x1.x - x3.x, x1.y - x3.y);
        float2 o[4];
        o[0] = make_float2(a.x + c.x, a.y + c.y);
        o[1] = make_float2(b.x - e.y, b.y + e.x);
        o[2] = make_float2(a.x - c.x, a.y - c.y);
        o[3] = make_float2(b.x + e.y, b.y - e.x);
        float cq[4] = {c1, -s1, -c1, s1};
        float sq[4] = {s1, c1, -s1, -c1};
        const float COSD = 0.99999529380958f;   // cos(pi/1024)
        const float SIND = 0.00306795676296f;   // sin(pi/1024)
#pragma unroll
        for (int q = 0; q < 4; ++q) {
            int n = t + 256 * q;
            float w0, w1;
            bool edge = (g == 0 && q < 2) || (g == 511 && q >= 2);
            if (edge) { w0 = 1.f; w1 = 1.f; }
            else {
                w0 = 0.5f - 0.5f * cq[q];
                w1 = 0.5f - 0.5f * (cq[q] * COSD - sq[q] * SIND);
            }
            ushort2 ov; ov.x = fbf16(o[q].x * w0); ov.y = fbf16(o[q].y * w1);
            awrow[n] = ov;
        }
    }
}

// ---------------- fused OLA gather + 65-tap conv + softsign ---------------
__global__ __launch_bounds__(256) void ola_ppconv_kernel(
    const ushort* __restrict__ awb, const float* __restrict__ ppw,
    const float* __restrict__ ppb, float* __restrict__ out)
{
    __shared__ float tile[320];
    __shared__ float Ksh[65];
    int t0 = blockIdx.x * 256;
    int b = blockIdx.y;
    const ushort* awbase = awb + ((size_t)(b * 512) << 11);
    for (int i = threadIdx.x; i < 320; i += 256) {
        int tt = t0 - 32 + i;
        float v = 0.f;
        if (tt >= 1536 && tt < 262144) {
            int glo = (tt - 1536) >> 9;
            const ushort* p = awbase + ((size_t)glo << 11) + (tt - (glo << 9));
            float s = bf16f(p[0]) + bf16f(p[1536]) + bf16f(p[3072]) + bf16f(p[4608]);
            v = s * 0.25f;
        } else if (tt >= 0 && tt < TARLEN) {
            int ghi = min(511, tt >> 9);
            int glo = max(0, (tt - 1536) >> 9);
            float s = 0.f;
            for (int g = glo; g <= ghi; ++g) {
                int n = tt - (g << 9);
                s += bf16f(awbase[((size_t)g << 11) + n]);
            }
            v = s / (float)(ghi - glo + 1);
        }
        tile[i] = v;
    }
    if (threadIdx.x < 65) {
        float k = 0.f;
#pragma unroll
        for (int c = 0; c < 5; ++c) k += ppw[c * 65 + threadIdx.x];
        Ksh[threadIdx.x] = k;
    }
    __syncthreads();
    float y = ppb[0];
#pragma unroll
    for (int j = 0; j < 65; ++j) y = fmaf(Ksh[j], tile[threadIdx.x + j], y);
    int t = t0 + threadIdx.x;
    out[(size_t)b * TARLEN + t] = y / (1.f + fabsf(y));
}

// ---------------- launch --------------------------------------------------
extern "C" void kernel_launch(void* const* d_in, const int* in_sizes, int n_in,
                              void* d_out, int out_size, void* d_ws, size_t ws_size,
                              hipStream_t stream) {
    const float* z    = (const float*)d_in[0];
    const float* w0   = (const float*)d_in[1];
    const float* b0   = (const float*)d_in[2];
    const float* g0   = (const float*)d_in[3];
    const float* be0  = (const float*)d_in[4];
    const float* w1   = (const float*)d_in[5];
    const float* b1   = (const float*)d_in[6];
    const float* g1   = (const float*)d_in[7];
    const float* be1  = (const float*)d_in[8];
    const float* w2   = (const float*)d_in[9];
    const float* b2   = (const float*)d_in[10];
    const float* g2   = (const float*)d_in[11];
    const float* be2  = (const float*)d_in[12];
    const float* w3   = (const float*)d_in[13];
    const float* b3   = (const float*)d_in[14];
    const float* ppw  = (const float*)d_in[15];
    const float* ppb  = (const float*)d_in[16];
    const float* noise= (const float*)d_in[17];
    float* out = (float*)d_out;
    float* ws = (float*)d_ws;

    // workspace (float offsets); ps/pq now 128 row-groups (128*512 f each)
    ushort* h0b = (ushort*)ws;                    // 8192*512 bf16
    ushort* h1b = (ushort*)(ws + 2097152);        // 8192*512 bf16
    float* ps0  = ws + 4194304;                   // 128*512
    float* pq0  = ps0 + 65536;
    float* ps1  = pq0 + 65536;
    float* pq1  = ps1 + 65536;
    float* base = pq1 + 65536;
    ushort* Bt0 = (ushort*)base;                  // 512*128 bf16
    ushort* Bt1 = (ushort*)(base + 32768);        // 512*512 bf16
    ushort* Bt2 = (ushort*)(base + 163840);       // 512*512 bf16
    ushort* Bt3 = (ushort*)(base + 294912);       // 1152*512 bf16
    ushort* fcsb= (ushort*)(base + 589824);       // 8192*1040 bf16
    ushort* awb = (ushort*)(base + 4849664);      // 8192*2048 bf16
    ushort* A   = (ushort*)(base + 13238272);     // 8192*128 bf16 (z cast)
    ushort* h2b = h0b;  // h0 dead after layer-1 consumed it

    dim3 blk(256);
    dim3 gblk(512);
    // input prep (4 weight transposes + z cast) in one launch
    prep_inputs<<<dim3(16, 36, 5), blk, 0, stream>>>(
        w0, w1, w2, w3, z, Bt0, Bt1, Bt2, Bt3, A);
    // layer 0: h0 = z @ w0 + b0 (+ stats -> S0, 64 groups); K=128
    gemm8<<<dim3(4, 64), gblk, 0, stream>>>(A, Bt0, b0, h0b, 128, ps0, pq0);
    // layer 1: fused BN(S0,64)+lrelu, gemm 64x128 tiles, stats -> S1 (128 groups)
    gemm4n<0><<<dim3(4, 128), blk, 0, stream>>>(
        h0b, Bt1, b1, ps0, pq0, 64, g0, be0, h1b, 512, 512, 512, ps1, pq1);
    // layer 2: fused BN(S1,128), stats -> S0 (128 groups)
    gemm4n<0><<<dim3(4, 128), blk, 0, stream>>>(
        h1b, Bt2, b2, ps1, pq1, 128, g1, be1, h2b, 512, 512, 512, ps0, pq0);
    // layer 3: fused BN(S0,128), mod_sigmoid -> fcsb [8192][1040], 1025 valid
    gemm4n<1><<<dim3(9, 128), blk, 0, stream>>>(
        h2b, Bt3, b3, ps0, pq0, 128, g2, be2, fcsb, 512, 1025, 1040, nullptr, nullptr);
    // spectral filtering + window (fused), bf16 in/out
    fft_filter_kernel<<<dim3(8192), blk, 0, stream>>>(noise, fcsb, awb);
    // fused OLA + post conv + softsign
    ola_ppconv_kernel<<<dim3(1030, 16), blk, 0, stream>>>(awb, ppw, ppb, out);
    (void)in_sizes; (void)n_in; (void)out_size; (void)ws_size;
}

// Round 18
// 159.002 us; speedup vs baseline: 1.3299x; 1.3299x over previous
//
#include <hip/hip_runtime.h>
#include <hip/hip_bf16.h>
#include <math.h>

#define TARLEN 263680
#define POWEXP 2.302585092994046f  // ln(10)
#define PC(i) ((i) + ((i) >> 3))   // complex-unit LDS padding (1 per 8)

typedef __attribute__((ext_vector_type(8))) short bf16x8;
typedef __attribute__((ext_vector_type(8))) ushort u16x8;
typedef __attribute__((ext_vector_type(4))) float f32x4;

__device__ __forceinline__ void gload16(const void* g, void* l) {
    __builtin_amdgcn_global_load_lds((const __attribute__((address_space(1))) void*)g,
                                     (__attribute__((address_space(3))) void*)l, 16, 0, 0);
}

__device__ __forceinline__ float bf16f(ushort u) {
    union { uint u; float f; } v; v.u = (uint)u << 16; return v.f;
}
__device__ __forceinline__ ushort fbf16(float x) {
    __hip_bfloat16 h = __float2bfloat16(x);
    return *reinterpret_cast<ushort*>(&h);
}

// sin/cos with input in REVOLUTIONS (v_sin_f32 native domain); args are exact
// binary fractions -> no rounding, no range reduction.
__device__ __forceinline__ float vsin_rev(float rev) {
    float r; asm("v_sin_f32 %0, %1" : "=v"(r) : "v"(rev)); return r;
}
__device__ __forceinline__ float vcos_rev(float rev) {
    float r; asm("v_cos_f32 %0, %1" : "=v"(r) : "v"(rev)); return r;
}

// ============ GEMM layer 0 (no norm): 128x128 tile, 512 thr =================
__global__ __launch_bounds__(512) void gemm8(
    const ushort* __restrict__ A, const ushort* __restrict__ Bt,
    const float* __restrict__ bias, ushort* __restrict__ C,
    int K, float* __restrict__ ps, float* __restrict__ pq)
{
    __shared__ ushort As[3][4096];
    __shared__ ushort Bs[3][4096];
    __shared__ float sred[8][2][16];
    __shared__ float qred[8][2][16];
    const int tid = threadIdx.x;
    const int lane = tid & 63;
    const int wid = tid >> 6;
    const int nwg = gridDim.x * gridDim.y;
    const int bid = blockIdx.y * gridDim.x + blockIdx.x;
    const int q8 = nwg >> 3;
    const int swzb = (bid & 7) * q8 + (bid >> 3);
    const int bx = swzb % gridDim.x;
    const int by = swzb / gridDim.x;
    const int m0 = by * 128;
    const int n0 = bx * 128;
    const int NT = K >> 5;

    f32x4 acc[4][2];
#pragma unroll
    for (int m = 0; m < 4; ++m)
#pragma unroll
        for (int n = 0; n < 2; ++n)
            acc[m][n] = (f32x4){0.f, 0.f, 0.f, 0.f};

    const int srow = tid >> 2;
    const int scol = (((tid & 3) ^ ((tid >> 3) & 3)) << 3);

    auto stage = [&](int t, int buf) {
        const int k0 = t << 5;
        gload16(A + (size_t)(m0 + srow) * K + k0 + scol, &As[buf][tid * 8]);
        gload16(Bt + (size_t)(n0 + srow) * K + k0 + scol, &Bs[buf][tid * 8]);
    };

    const int lr = lane & 15;
    const int sw8 = (((lane >> 4) ^ ((lane >> 1) & 3)) << 3);
    const int wm0 = (wid >> 2) * 64;
    const int wn0 = (wid & 3) * 32;

    stage(0, 0);
    stage(1, 1);
    for (int t = 0; t < NT; ++t) {
        const int cur = t % 3;
        if (t + 2 < NT) {
            asm volatile("s_waitcnt vmcnt(2)" ::: "memory");
            __builtin_amdgcn_s_barrier();
            stage(t + 2, (t + 2) % 3);
        } else {
            asm volatile("s_waitcnt vmcnt(0)" ::: "memory");
            __builtin_amdgcn_s_barrier();
        }
        const ushort* as = As[cur];
        const ushort* bs = Bs[cur];
        bf16x8 af[4], bfv[2];
#pragma unroll
        for (int m = 0; m < 4; ++m)
            af[m] = *reinterpret_cast<const bf16x8*>(&as[(wm0 + m * 16 + lr) * 32 + sw8]);
#pragma unroll
        for (int n = 0; n < 2; ++n)
            bfv[n] = *reinterpret_cast<const bf16x8*>(&bs[(wn0 + n * 16 + lr) * 32 + sw8]);
#pragma unroll
        for (int m = 0; m < 4; ++m)
#pragma unroll
            for (int n = 0; n < 2; ++n)
                acc[m][n] = __builtin_amdgcn_mfma_f32_16x16x32_bf16(af[m], bfv[n], acc[m][n], 0, 0, 0);
    }
    __syncthreads();

    const int cr = (lane >> 4) << 2;
    const int cc = lane & 15;
    float sacc[2] = {0.f, 0.f}, qacc[2] = {0.f, 0.f};
#pragma unroll
    for (int m = 0; m < 4; ++m) {
#pragma unroll
        for (int n = 0; n < 2; ++n) {
            int gcol = n0 + wn0 + n * 16 + cc;
            float bv = bias[gcol];
            int grow = m0 + wm0 + m * 16 + cr;
#pragma unroll
            for (int j = 0; j < 4; ++j) {
                float v = acc[m][n][j] + bv;
                sacc[n] += v;
                qacc[n] += v * v;
                C[(size_t)(grow + j) * 512 + gcol] = fbf16(v);
            }
        }
    }
#pragma unroll
    for (int n = 0; n < 2; ++n) {
        float s = sacc[n], q = qacc[n];
        s += __shfl_xor(s, 16); q += __shfl_xor(q, 16);
        s += __shfl_xor(s, 32); q += __shfl_xor(q, 32);
        if (lane < 16) { sred[wid][n][lane] = s; qred[wid][n][lane] = q; }
    }
    __syncthreads();
    if (tid < 128) {
        int wn_ = tid >> 5, n_ = (tid >> 4) & 1, cc_ = tid & 15;
        float s = sred[wn_][n_][cc_] + sred[4 + wn_][n_][cc_];
        float q = qred[wn_][n_][cc_] + qred[4 + wn_][n_][cc_];
        int col = n0 + wn_ * 32 + n_ * 16 + cc_;
        ps[(size_t)by * 512 + col] = s;
        pq[(size_t)by * 512 + col] = q;
    }
}

// ============ GEMM with fused BN (stats reduce + affine + lrelu on A) =======
template<int EPI>
__global__ __launch_bounds__(512) void gemm8n(
    const ushort* __restrict__ H, const ushort* __restrict__ Bt,
    const float* __restrict__ bias,
    const float* __restrict__ psIn, const float* __restrict__ pqIn,
    const float* __restrict__ gamma, const float* __restrict__ beta,
    ushort* __restrict__ C, int K, int Nvalid, int ldc,
    float* __restrict__ psOut, float* __restrict__ pqOut)
{
    __shared__ ushort As[3][4096];
    __shared__ ushort Bs[3][4096];
    __shared__ uint sab[512];
    __shared__ float sred[8][2][16];
    __shared__ float qred[8][2][16];
    const int tid = threadIdx.x;
    const int lane = tid & 63;
    const int wid = tid >> 6;
    const int nwg = gridDim.x * gridDim.y;
    const int bid = blockIdx.y * gridDim.x + blockIdx.x;
    const int q8 = nwg >> 3;
    const int swzb = (bid & 7) * q8 + (bid >> 3);
    const int bx = swzb % gridDim.x;
    const int by = swzb / gridDim.x;
    const int m0 = by * 128;
    const int n0 = bx * 128;
    const int NT = K >> 5;  // even (K=512)

    {
        int c = tid;
        float s = 0.f, q = 0.f;
#pragma unroll 8
        for (int rg = 0; rg < 64; ++rg) { s += psIn[rg * 512 + c]; q += pqIn[rg * 512 + c]; }
        float m = s * (1.f / 8192.f);
        float v = q * (1.f / 8192.f) - m * m;
        float a = rsqrtf(v + 1e-5f) * gamma[c];
        float b = beta[c] - m * a;
        sab[c] = (uint)fbf16(a) | ((uint)fbf16(b) << 16);
    }

    f32x4 acc[4][2];
#pragma unroll
    for (int m = 0; m < 4; ++m)
#pragma unroll
        for (int n = 0; n < 2; ++n)
            acc[m][n] = (f32x4){0.f, 0.f, 0.f, 0.f};

    const int srow = tid >> 2;
    const int scol = (((tid & 3) ^ ((tid >> 3) & 3)) << 3);
    const int lr = lane & 15;
    const int sw8 = (((lane >> 4) ^ ((lane >> 1) & 3)) << 3);
    const int wm0 = (wid >> 2) * 64;
    const int wn0 = (wid & 3) * 32;

    const size_t arow = (size_t)(m0 + srow) * K + scol;
    const size_t brow = (size_t)(n0 + srow) * K + scol;

    auto stageB = [&](int t, int buf) {
        gload16(Bt + brow + (t << 5), &Bs[buf][tid * 8]);
    };
    auto loadA = [&](int t, u16x8& dst) {
        dst = *reinterpret_cast<const u16x8*>(H + arow + (t << 5));
    };

    __syncthreads();  // sab ready

    u16x8 a0, a1;
    stageB(0, 0); loadA(0, a0);
    stageB(1, 1); loadA(1, a1);

    auto iter = [&](int t, u16x8& ar) {
        const int cur = t % 3;
        if (t + 2 < NT) asm volatile("s_waitcnt vmcnt(2)" ::: "memory");
        else            asm volatile("s_waitcnt vmcnt(0)" ::: "memory");
        {
            const uint* pk = &sab[(t << 5) + scol];
            u16x8 o;
#pragma unroll
            for (int j = 0; j < 8; ++j) {
                uint w = pk[j];
                float a = bf16f((ushort)(w & 0xffffu));
                float b = bf16f((ushort)(w >> 16));
                float y = fmaf(bf16f(ar[j]), a, b);
                o[j] = fbf16(y >= 0.f ? y : 0.2f * y);
            }
            *reinterpret_cast<u16x8*>(&As[cur][tid * 8]) = o;
        }
        asm volatile("s_waitcnt lgkmcnt(0)" ::: "memory");
        __builtin_amdgcn_s_barrier();
        if (t + 2 < NT) { stageB(t + 2, (t + 2) % 3); loadA(t + 2, ar); }
        const ushort* as = As[cur];
        const ushort* bs = Bs[cur];
        bf16x8 af[4], bfv[2];
#pragma unroll
        for (int m = 0; m < 4; ++m)
            af[m] = *reinterpret_cast<const bf16x8*>(&as[(wm0 + m * 16 + lr) * 32 + sw8]);
#pragma unroll
        for (int n = 0; n < 2; ++n)
            bfv[n] = *reinterpret_cast<const bf16x8*>(&bs[(wn0 + n * 16 + lr) * 32 + sw8]);
#pragma unroll
        for (int m = 0; m < 4; ++m)
#pragma unroll
            for (int n = 0; n < 2; ++n)
                acc[m][n] = __builtin_amdgcn_mfma_f32_16x16x32_bf16(af[m], bfv[n], acc[m][n], 0, 0, 0);
    };

    for (int t = 0; t < NT; t += 2) { iter(t, a0); iter(t + 1, a1); }
    __syncthreads();

    const int cr = (lane >> 4) << 2;
    const int cc = lane & 15;
    float sacc[2] = {0.f, 0.f}, qacc[2] = {0.f, 0.f};
#pragma unroll
    for (int m = 0; m < 4; ++m) {
#pragma unroll
        for (int n = 0; n < 2; ++n) {
            int gcol = n0 + wn0 + n * 16 + cc;
            if (EPI == 0 || gcol < Nvalid) {
                float bv = bias[gcol];
                int grow = m0 + wm0 + m * 16 + cr;
#pragma unroll
                for (int j = 0; j < 4; ++j) {
                    float v = acc[m][n][j] + bv;
                    if (EPI == 1) {
                        float sg = 1.f / (1.f + __expf(-v));
                        v = 2.f * __expf(POWEXP * __logf(sg)) + 1e-7f;
                    } else {
                        sacc[n] += v;
                        qacc[n] += v * v;
                    }
                    C[(size_t)(grow + j) * ldc + gcol] = fbf16(v);
                }
            }
        }
    }
    if (EPI == 0) {
#pragma unroll
        for (int n = 0; n < 2; ++n) {
            float s = sacc[n], q = qacc[n];
            s += __shfl_xor(s, 16); q += __shfl_xor(q, 16);
            s += __shfl_xor(s, 32); q += __shfl_xor(q, 32);
            if (lane < 16) { sred[wid][n][lane] = s; qred[wid][n][lane] = q; }
        }
        __syncthreads();
        if (tid < 128) {
            int wn_ = tid >> 5, n_ = (tid >> 4) & 1, cc_ = tid & 15;
            float s = sred[wn_][n_][cc_] + sred[4 + wn_][n_][cc_];
            float q = qred[wn_][n_][cc_] + qred[4 + wn_][n_][cc_];
            int col = n0 + wn_ * 32 + n_ * 16 + cc_;
            psOut[(size_t)by * 512 + col] = s;
            pqOut[(size_t)by * 512 + col] = q;
        }
    }
}

// ---------------- batched input prep: 4 weight transposes + z cast --------
__global__ __launch_bounds__(256) void prep_inputs(
    const float* __restrict__ w0, const float* __restrict__ w1,
    const float* __restrict__ w2, const float* __restrict__ w3,
    const float* __restrict__ z,
    ushort* __restrict__ B0, ushort* __restrict__ B1,
    ushort* __restrict__ B2, ushort* __restrict__ B3,
    ushort* __restrict__ A)
{
    if (blockIdx.z == 4) {
        int bid = blockIdx.y * gridDim.x + blockIdx.x;
        if (bid >= 512) return;
        int idx = (bid * 256 + threadIdx.x) << 3;
        float4 a = *reinterpret_cast<const float4*>(&z[idx]);
        float4 b = *reinterpret_cast<const float4*>(&z[idx + 4]);
        float x[8] = {a.x, a.y, a.z, a.w, b.x, b.y, b.z, b.w};
        u16x8 o;
#pragma unroll
        for (int j = 0; j < 8; ++j) o[j] = fbf16(x[j]);
        *reinterpret_cast<u16x8*>(&A[idx]) = o;
        return;
    }
    const float* w; ushort* Bt; int K, N, GX, GY;
    switch (blockIdx.z) {
        case 0: w = w0; Bt = B0; K = 128; N = 512;  GX = 4;  GY = 16; break;
        case 1: w = w1; Bt = B1; K = 512; N = 512;  GX = 16; GY = 16; break;
        case 2: w = w2; Bt = B2; K = 512; N = 512;  GX = 16; GY = 16; break;
        default:w = w3; Bt = B3; K = 512; N = 1025; GX = 16; GY = 36; break;
    }
    if ((int)blockIdx.x >= GX || (int)blockIdx.y >= GY) return;
    __shared__ float tile[32][33];
    int k0 = blockIdx.x * 32, n0 = blockIdx.y * 32;
    int tx = threadIdx.x & 31, ty = threadIdx.x >> 5;
#pragma unroll
    for (int r = 0; r < 4; ++r) {
        int k = k0 + ty + r * 8;
        int n = n0 + tx;
        tile[ty + r * 8][tx] = (n < N) ? w[(size_t)k * N + n] : 0.f;
    }
    __syncthreads();
#pragma unroll
    for (int r = 0; r < 4; ++r) {
        int n = n0 + ty + r * 8;
        int k = k0 + tx;
        Bt[(size_t)n * K + k] = fbf16(tile[tx][ty + r * 8]);
    }
}

// ---------------- Stockham radix-4 FFT, float2 LDS, 256 threads -----------
__device__ __forceinline__ float2 cmul(float2 a, float c, float s) {
    return make_float2(a.x * c - a.y * s, a.x * s + a.y * c);
}

template<bool INV, int L>
__device__ __forceinline__ void stk_stage(
    const float2* __restrict__ s, float2* __restrict__ d, int t)
{
    int k = t & (L - 1);
    float2 x0 = s[PC(t)];
    float2 x1 = s[PC(t + 256)];
    float2 x2 = s[PC(t + 512)];
    float2 x3 = s[PC(t + 768)];
    if (L > 1) {
        float rev = (float)k * (1.0f / (float)(4 * L));
        float s1 = vsin_rev(rev), c1 = vcos_rev(rev);
        if (!INV) s1 = -s1;
        float c2 = c1 * c1 - s1 * s1, s2 = 2.f * c1 * s1;
        float c3 = c2 * c1 - s2 * s1, s3 = s2 * c1 + c2 * s1;
        x1 = cmul(x1, c1, s1);
        x2 = cmul(x2, c2, s2);
        x3 = cmul(x3, c3, s3);
    }
    float2 a = make_float2(x0.x + x2.x, x0.y + x2.y);
    float2 b = make_float2(x0.x - x2.x, x0.y - x2.y);
    float2 c = make_float2(x1.x + x3.x, x1.y + x3.y);
    float2 e = make_float2(x1.x - x3.x, x1.y - x3.y);
    int db = ((t - k) << 2) + k;
    d[PC(db)]         = make_float2(a.x + c.x, a.y + c.y);
    d[PC(db + 2 * L)] = make_float2(a.x - c.x, a.y - c.y);
    if (!INV) {
        d[PC(db + L)]     = make_float2(b.x + e.y, b.y - e.x);
        d[PC(db + 3 * L)] = make_float2(b.x - e.y, b.y + e.x);
    } else {
        d[PC(db + L)]     = make_float2(b.x - e.y, b.y + e.x);
        d[PC(db + 3 * L)] = make_float2(b.x + e.y, b.y - e.x);
    }
}

// audio = irfft( rfft(noise_row) * H ), H[k] = (-1)^k*(0.5 fc[k]+0.25 fc[k-1]+0.25 fc[k+1])
// (analytic collapse of rfft(fftshift(irfft(fc)*FW))). 1/1024 folded into H.
__global__ __launch_bounds__(256) void fft_filter_kernel(
    const float* __restrict__ noise, const ushort* __restrict__ fcsb,
    ushort* __restrict__ awb)
{
    __shared__ float2 X[1152], Y[1152];
    __shared__ float F[1025];
    const int tid = threadIdx.x;
    const int r = blockIdx.x;

    const float2* nrow = reinterpret_cast<const float2*>(noise + ((size_t)r << 11));
    for (int i = tid; i < 1025; i += 256) F[i] = bf16f(fcsb[(size_t)r * 1040 + i]);
    {
        float2 x0 = nrow[tid], x1 = nrow[tid + 256], x2 = nrow[tid + 512], x3 = nrow[tid + 768];
        float2 a = make_float2(x0.x + x2.x, x0.y + x2.y);
        float2 b = make_float2(x0.x - x2.x, x0.y - x2.y);
        float2 c = make_float2(x1.x + x3.x, x1.y + x3.y);
        float2 e = make_float2(x1.x - x3.x, x1.y - x3.y);
        int db = tid << 2;
        Y[PC(db)]     = make_float2(a.x + c.x, a.y + c.y);
        Y[PC(db + 1)] = make_float2(b.x + e.y, b.y - e.x);
        Y[PC(db + 2)] = make_float2(a.x - c.x, a.y - c.y);
        Y[PC(db + 3)] = make_float2(b.x - e.y, b.y + e.x);
    }
    __syncthreads();
    stk_stage<false, 4>(Y, X, tid);   __syncthreads();
    stk_stage<false, 16>(X, Y, tid);  __syncthreads();
    stk_stage<false, 64>(Y, X, tid);  __syncthreads();
    stk_stage<false, 256>(X, Y, tid); __syncthreads();

    const float INV1024 = 1.0f / 1024.0f;
    auto proc = [&](int k, float c, float s) {
        int k2 = (1024 - k) & 1023;
        float2 za = Y[PC(k)], zb = Y[PC(k2)];
        float Fer = 0.5f * (za.x + zb.x), Fei = 0.5f * (za.y - zb.y);
        float For = 0.5f * (za.y + zb.y), Foi = 0.5f * (zb.x - za.x);
        float wFr = c * For - s * Foi;
        float wFi = c * Foi + s * For;
        float Xkr = Fer + wFr, Xki = Fei + wFi;
        float Xbr = Fer - wFr, Xbi = wFi - Fei;
        float Hk, Hb;
        {
            float cl = (k == 0) ? F[1] : F[k - 1];
            float crr = (k == 1024) ? F[1023] : F[k + 1];
            float h = 0.5f * F[k] + 0.25f * (cl + crr);
            Hk = ((k & 1) ? -h : h) * INV1024;
        }
        {
            int kb = 1024 - k;
            float cl = (kb == 0) ? F[1] : F[kb - 1];
            float crr = (kb == 1024) ? F[1023] : F[kb + 1];
            float h = 0.5f * F[kb] + 0.25f * (cl + crr);
            Hb = ((kb & 1) ? -h : h) * INV1024;
        }
        float Ykr = Hk * Xkr, Yki = Hk * Xki;
        float Ybr = Hb * Xbr, Ybi = Hb * Xbi;
        if (k == 0) {
            X[PC(0)] = make_float2(0.5f * (Ykr + Ybr), 0.5f * (Ykr - Ybr));
        } else {
            float Ger = 0.5f * (Ykr + Ybr), Gei = 0.5f * (Yki - Ybi);
            float Sgr = 0.5f * (Ykr - Ybr), Sgi = 0.5f * (Yki + Ybi);
            float wpr = c, wpi = -s;
            float Gor = wpr * Sgr - wpi * Sgi;
            float Goi = wpr * Sgi + wpi * Sgr;
            X[PC(k)]  = make_float2(Ger - Goi, Gei + Gor);
            X[PC(k2)] = make_float2(Ger + Goi, Gor - Gei);
        }
    };
    {
        float rev0 = (float)tid * (1.0f / 2048.0f);
        float c0 = vcos_rev(rev0), s0 = -vsin_rev(rev0);
        proc(tid, c0, s0);
        float rev1 = (float)(tid + 256) * (1.0f / 2048.0f);
        float c1 = vcos_rev(rev1), s1 = -vsin_rev(rev1);
        proc(tid + 256, c1, s1);
        if (tid == 0) proc(512, 0.f, -1.f);
    }
    __syncthreads();

    stk_stage<true, 1>(X, Y, tid);  __syncthreads();
    stk_stage<true, 4>(Y, X, tid);  __syncthreads();
    stk_stage<true, 16>(X, Y, tid); __syncthreads();
    stk_stage<true, 64>(Y, X, tid); __syncthreads();

    {
        const int g = r & 511;
        ushort2* awrow = reinterpret_cast<ushort2*>(awb + ((size_t)r << 11));
        int t = tid;
        float2 x0 = X[PC(t)], x1 = X[PC(t + 256)], x2 = X[PC(t + 512)], x3 = X[PC(t + 768)];
        float rev = (float)t * (1.0f / 1024.0f);
        float s1 = vsin_rev(rev), c1 = vcos_rev(rev);
        float c2 = c1 * c1 - s1 * s1, s2 = 2.f * c1 * s1;
        float c3 = c2 * c1 - s2 * s1, s3 = s2 * c1 + c2 * s1;
        x1 = cmul(x1, c1, s1);
        x2 = cmul(x2, c2, s2);
        x3 = cmul(x3, c3, s3);
        float2 a = make_float2(x0.x + x2.x, x0.y + x2.y);
        float2 b = make_float2(x0.x - x2.x, x0.y - x2.y);
        float2 c = make_float2(x1.x + x3.x, x1.y + x3.y);
        float2 e = make_float2(x1.x - x3.x, x1.y - x3.y);
        float2 o[4];
        o[0] = make_float2(a.x + c.x, a.y + c.y);
        o[1] = make_float2(b.x - e.y, b.y + e.x);
        o[2] = make_float2(a.x - c.x, a.y - c.y);
        o[3] = make_float2(b.x + e.y, b.y - e.x);
        float cq[4] = {c1, -s1, -c1, s1};
        float sq[4] = {s1, c1, -s1, -c1};
        const float COSD = 0.99999529380958f;   // cos(pi/1024)
        const float SIND = 0.00306795676296f;   // sin(pi/1024)
#pragma unroll
        for (int q = 0; q < 4; ++q) {
            int n = t + 256 * q;
            float w0, w1;
            bool edge = (g == 0 && q < 2) || (g == 511 && q >= 2);
            if (edge) { w0 = 1.f; w1 = 1.f; }
            else {
                w0 = 0.5f - 0.5f * cq[q];
                w1 = 0.5f - 0.5f * (cq[q] * COSD - sq[q] * SIND);
            }
            ushort2 ov; ov.x = fbf16(o[q].x * w0); ov.y = fbf16(o[q].y * w1);
            awrow[n] = ov;
        }
    }
}

// ---------------- fused OLA gather + 65-tap conv + softsign ---------------
__global__ __launch_bounds__(256) void ola_ppconv_kernel(
    const ushort* __restrict__ awb, const float* __restrict__ ppw,
    const float* __restrict__ ppb, float* __restrict__ out)
{
    __shared__ float tile[320];
    __shared__ float Ksh[65];
    int t0 = blockIdx.x * 256;
    int b = blockIdx.y;
    const ushort* awbase = awb + ((size_t)(b * 512) << 11);
    for (int i = threadIdx.x; i < 320; i += 256) {
        int tt = t0 - 32 + i;
        float v = 0.f;
        if (tt >= 1536 && tt < 262144) {
            int glo = (tt - 1536) >> 9;
            const ushort* p = awbase + ((size_t)glo << 11) + (tt - (glo << 9));
            float s = bf16f(p[0]) + bf16f(p[1536]) + bf16f(p[3072]) + bf16f(p[4608]);
            v = s * 0.25f;
        } else if (tt >= 0 && tt < TARLEN) {
            int ghi = min(511, tt >> 9);
            int glo = max(0, (tt - 1536) >> 9);
            float s = 0.f;
            for (int g = glo; g <= ghi; ++g) {
                int n = tt - (g << 9);
                s += bf16f(awbase[((size_t)g << 11) + n]);
            }
            v = s / (float)(ghi - glo + 1);
        }
        tile[i] = v;
    }
    if (threadIdx.x < 65) {
        float k = 0.f;
#pragma unroll
        for (int c = 0; c < 5; ++c) k += ppw[c * 65 + threadIdx.x];
        Ksh[threadIdx.x] = k;
    }
    __syncthreads();
    float y = ppb[0];
#pragma unroll
    for (int j = 0; j < 65; ++j) y = fmaf(Ksh[j], tile[threadIdx.x + j], y);
    int t = t0 + threadIdx.x;
    out[(size_t)b * TARLEN + t] = y / (1.f + fabsf(y));
}

// ---------------- launch --------------------------------------------------
extern "C" void kernel_launch(void* const* d_in, const int* in_sizes, int n_in,
                              void* d_out, int out_size, void* d_ws, size_t ws_size,
                              hipStream_t stream) {
    const float* z    = (const float*)d_in[0];
    const float* w0   = (const float*)d_in[1];
    const float* b0   = (const float*)d_in[2];
    const float* g0   = (const float*)d_in[3];
    const float* be0  = (const float*)d_in[4];
    const float* w1   = (const float*)d_in[5];
    const float* b1   = (const float*)d_in[6];
    const float* g1   = (const float*)d_in[7];
    const float* be1  = (const float*)d_in[8];
    const float* w2   = (const float*)d_in[9];
    const float* b2   = (const float*)d_in[10];
    const float* g2   = (const float*)d_in[11];
    const float* be2  = (const float*)d_in[12];
    const float* w3   = (const float*)d_in[13];
    const float* b3   = (const float*)d_in[14];
    const float* ppw  = (const float*)d_in[15];
    const float* ppb  = (const float*)d_in[16];
    const float* noise= (const float*)d_in[17];
    float* out = (float*)d_out;
    float* ws = (float*)d_ws;

    // workspace (float offsets)
    ushort* h0b = (ushort*)ws;                    // 8192*512 bf16
    ushort* h1b = (ushort*)(ws + 2097152);        // 8192*512 bf16
    float* ps0  = ws + 4194304;                   // 64*512
    float* pq0  = ps0 + 32768;
    float* ps1  = pq0 + 32768;
    float* pq1  = ps1 + 32768;
    float* base = pq1 + 32768;
    ushort* Bt0 = (ushort*)base;                  // 512*128 bf16
    ushort* Bt1 = (ushort*)(base + 32768);        // 512*512 bf16
    ushort* Bt2 = (ushort*)(base + 163840);       // 512*512 bf16
    ushort* Bt3 = (ushort*)(base + 294912);       // 1152*512 bf16
    ushort* fcsb= (ushort*)(base + 589824);       // 8192*1040 bf16
    ushort* awb = (ushort*)(base + 4849664);      // 8192*2048 bf16
    ushort* A   = (ushort*)(base + 13238272);     // 8192*128 bf16 (z cast)
    ushort* h2b = h0b;  // h0 dead after gemm1 consumed it

    dim3 blk(256);
    dim3 gblk(512);
    // input prep (4 weight transposes + z cast) in one launch
    prep_inputs<<<dim3(16, 36, 5), blk, 0, stream>>>(
        w0, w1, w2, w3, z, Bt0, Bt1, Bt2, Bt3, A);
    // layer 0: h0 = z @ w0 + b0 (+ stats -> S0); K=128
    gemm8<<<dim3(4, 64), gblk, 0, stream>>>(A, Bt0, b0, h0b, 128, ps0, pq0);
    // layer 1: fused BN(S0)+lrelu on A, gemm, stats -> S1
    gemm8n<0><<<dim3(4, 64), gblk, 0, stream>>>(
        h0b, Bt1, b1, ps0, pq0, g0, be0, h1b, 512, 512, 512, ps1, pq1);
    // layer 2: fused BN(S1), stats -> S0
    gemm8n<0><<<dim3(4, 64), gblk, 0, stream>>>(
        h1b, Bt2, b2, ps1, pq1, g1, be1, h2b, 512, 512, 512, ps0, pq0);
    // layer 3: fused BN(S0), mod_sigmoid -> fcsb [8192][1040], 1025 valid
    gemm8n<1><<<dim3(9, 64), gblk, 0, stream>>>(
        h2b, Bt3, b3, ps0, pq0, g2, be2, fcsb, 512, 1025, 1040, nullptr, nullptr);
    // spectral filtering + window (fused), bf16 in/out
    fft_filter_kernel<<<dim3(8192), blk, 0, stream>>>(noise, fcsb, awb);
    // fused OLA + post conv + softsign
    ola_ppconv_kernel<<<dim3(1030, 16), blk, 0, stream>>>(awb, ppw, ppb, out);
    (void)in_sizes; (void)n_in; (void)out_size; (void)ws_size;
}